// Round 1
// baseline (911.354 us; speedup 1.0000x reference)
//
#include <hip/hip_runtime.h>

// Problem constants (from reference setup_inputs)
#define B 256
#define K 32
#define D 2048
#define N 100000
#define CHUNK 1024                 // d-elements per block (phase B)
#define NBLK (B * (D / CHUNK))     // 512 blocks
#define MATCH_WEIGHT 80.0f

// ---------------------------------------------------------------------------
// Phase A: gather the needed W values into a compact Tt[d][b] (D x B floats,
// 2 MB, lives in workspace).
//   block d (0..D-1), thread t (= batch b, 0..B-1):
//     read  W[d*N + idx[t]]  -> 64 random columns of ONE row per wave
//                               (row = 400 KB contiguous => 1-2 pages, vs the
//                               old pattern's 64 pages per instruction)
//     write Tt[d*B + t]      -> fully coalesced 1 KB store per wave
// 2048 blocks x 4 waves = 8192 waves => max occupancy to hide the random-line
// HBM latency.
// ---------------------------------------------------------------------------
__global__ __launch_bounds__(256)
void gather_kernel(const float* __restrict__ W,
                   const int*   __restrict__ idx,
                   float* __restrict__ Tt)
{
    const int d = blockIdx.x;
    const int t = threadIdx.x;          // t == b
    const int col = idx[t];
    Tt[(size_t)d * B + t] = W[(size_t)d * N + (size_t)col];
}

// ---------------------------------------------------------------------------
// Phase B: the verified streaming reduction, but the per-thread target values
// come from the 2 MB cache-hot Tt instead of 1.6MB-strided HBM reads.
// ---------------------------------------------------------------------------
__global__ __launch_bounds__(256)
void reduce_kernel(const float* __restrict__ e,   // [B,K,D]
                   const float* __restrict__ Tt,  // [D,B]
                   float* __restrict__ out)
{
    const int blk = blockIdx.x;
    const int b   = blk >> 1;            // D/CHUNK == 2
    const int d0  = (blk & 1) * CHUNK;
    const int t   = threadIdx.x;
    const int d   = d0 + t * 4;          // this thread's 4 d-indices

    // 4 scalar loads from the 2 MB Tt buffer (L2/L3 resident). Lane stride is
    // 4*B*4B = 4 KB -- uncoalesced but cache-hit; issued once per thread and
    // hidden under the 32 streaming e loads.
    const float t0 = Tt[(size_t)(d + 0) * B + b];
    const float t1 = Tt[(size_t)(d + 1) * B + b];
    const float t2 = Tt[(size_t)(d + 2) * B + b];
    const float t3 = Tt[(size_t)(d + 3) * B + b];

    // Coalesced float4 reads of e over the k dimension.
    const float* ebase = e + (size_t)b * K * D + d0 + (size_t)t * 4;
    float acc = 0.0f;
#pragma unroll 8
    for (int k = 0; k < K; ++k) {
        const float4 v = *(const float4*)(ebase + (size_t)k * D);
        acc += fabsf(v.x - t0) + fabsf(v.y - t1)
             + fabsf(v.z - t2) + fabsf(v.w - t3);
    }

    // Wave(64)-wide shuffle reduction, then cross-wave via LDS.
    for (int off = 32; off > 0; off >>= 1)
        acc += __shfl_down(acc, off, 64);

    __shared__ float wsum[4];            // 256 threads = 4 waves
    const int wave = t >> 6;
    if ((t & 63) == 0) wsum[wave] = acc;
    __syncthreads();

    if (t == 0) {
        const float s = wsum[0] + wsum[1] + wsum[2] + wsum[3];
        const float scale = MATCH_WEIGHT / (float)((size_t)B * K * D);
        atomicAdd(out, s * scale);
    }
}

// ---------------------------------------------------------------------------
// Fallback (the previous verified single-kernel path) in case the workspace
// is too small for Tt.
// ---------------------------------------------------------------------------
__global__ __launch_bounds__(256)
void loss_match_kernel(const float* __restrict__ e,
                       const float* __restrict__ W,
                       const int*   __restrict__ idx,
                       float* __restrict__ out)
{
    const int blk = blockIdx.x;
    const int b   = blk >> 1;
    const int d0  = (blk & 1) * CHUNK;
    const int t   = threadIdx.x;

    const int col = idx[b];
    const int d   = d0 + t * 4;

    const size_t wbase = (size_t)d * N + (size_t)col;
    const float t0 = W[wbase];
    const float t1 = W[wbase + (size_t)N];
    const float t2 = W[wbase + 2ull * N];
    const float t3 = W[wbase + 3ull * N];

    const float* ebase = e + (size_t)b * K * D + d0 + (size_t)t * 4;
    float acc = 0.0f;
#pragma unroll 8
    for (int k = 0; k < K; ++k) {
        const float4 v = *(const float4*)(ebase + (size_t)k * D);
        acc += fabsf(v.x - t0) + fabsf(v.y - t1)
             + fabsf(v.z - t2) + fabsf(v.w - t3);
    }

    for (int off = 32; off > 0; off >>= 1)
        acc += __shfl_down(acc, off, 64);

    __shared__ float wsum[4];
    const int wave = t >> 6;
    if ((t & 63) == 0) wsum[wave] = acc;
    __syncthreads();

    if (t == 0) {
        const float s = wsum[0] + wsum[1] + wsum[2] + wsum[3];
        const float scale = MATCH_WEIGHT / (float)((size_t)B * K * D);
        atomicAdd(out, s * scale);
    }
}

extern "C" void kernel_launch(void* const* d_in, const int* in_sizes, int n_in,
                              void* d_out, int out_size, void* d_ws, size_t ws_size,
                              hipStream_t stream) {
    const float* e   = (const float*)d_in[0];
    const float* W   = (const float*)d_in[1];
    const int*   idx = (const int*)d_in[2];
    float* out = (float*)d_out;

    // d_out is poisoned before every timed launch -- zero it.
    hipMemsetAsync(out, 0, (size_t)out_size * sizeof(float), stream);

    const size_t t_bytes = (size_t)D * B * sizeof(float);   // 2 MB
    if (ws_size >= t_bytes && d_ws != nullptr) {
        float* Tt = (float*)d_ws;
        gather_kernel<<<D, 256, 0, stream>>>(W, idx, Tt);
        reduce_kernel<<<NBLK, 256, 0, stream>>>(e, Tt, out);
    } else {
        loss_match_kernel<<<NBLK, 256, 0, stream>>>(e, W, idx, out);
    }
}